// Round 1
// baseline (1426.161 us; speedup 1.0000x reference)
//
#include <hip/hip_runtime.h>
#include <hip/hip_bf16.h>
#include <math.h>

#define IN_DIM 128
#define HID_DIM 64

// ---------------------------------------------------------------------------
// fast tanh: tanh(x) = sign(x) * (1 - z) / (1 + z),  z = exp(-2|x|)
// v_exp_f32 + v_rcp_f32, ~1-2 ulp — far inside the 1.39e-2 absmax threshold.
// ---------------------------------------------------------------------------
__device__ __forceinline__ float fast_tanh(float x) {
    float ax = fabsf(x);
    float z  = __expf(-2.0f * ax);
    float t  = (1.0f - z) * __builtin_amdgcn_rcpf(1.0f + z);
    return copysignf(t, x);
}

// ---------------------------------------------------------------------------
// K1: per-node score. lane = node. y[64] accumulators live in VGPRs, w1 reads
// are wave-uniform -> scalar loads (SGPR src operand on v_fma), h streamed as
// float4 per lane. |s| <= ||w2||_1 (~6.4) so exp(s) never overflows: we skip
// the segment-max pass entirely (mathematically identical softmax).
// Writes e[i]=exp(s_i) and atomically accumulates denom[batch[i]].
// ---------------------------------------------------------------------------
extern "C" __global__ __launch_bounds__(256) void k_score(
    const float* __restrict__ H, const float* __restrict__ w1,
    const float* __restrict__ w2, const int* __restrict__ batch,
    float* __restrict__ e_arr, float* __restrict__ denom, int n)
{
    int i = blockIdx.x * 256 + threadIdx.x;
    if (i >= n) return;

    const float4* h4 = (const float4*)(H + (size_t)i * IN_DIM);

    float y[HID_DIM];
#pragma unroll
    for (int j = 0; j < HID_DIM; ++j) y[j] = 0.0f;

    // kt rolled (unroll 2) to keep I$ reasonable: body = 512 FMA + uniform w1
    // loads. j fully unrolled -> y[j] stays in registers, FMAs independent.
#pragma unroll 2
    for (int kt = 0; kt < IN_DIM / 4; ++kt) {
        float4 h = h4[kt];
#pragma unroll
        for (int j = 0; j < HID_DIM; ++j) {
            const float* wr = w1 + j * IN_DIM + kt * 4;
            float a = y[j];
            a = fmaf(wr[0], h.x, a);
            a = fmaf(wr[1], h.y, a);
            a = fmaf(wr[2], h.z, a);
            a = fmaf(wr[3], h.w, a);
            y[j] = a;
        }
    }

    float s = 0.0f;
#pragma unroll
    for (int j = 0; j < HID_DIM; ++j)
        s = fmaf(w2[j], fast_tanh(y[j]), s);

    float e = __expf(s);
    e_arr[i] = e;
    atomicAdd(&denom[batch[i]], e);
}

// ---------------------------------------------------------------------------
// K2: segment-softmax-weighted feature sum, exploiting SORTED batch.
// 32-lane group owns 32 contiguous nodes; lane owns dims [4*lane, 4*lane+4)
// (float4 -> perfectly coalesced 512 B per group per node). e/batch loaded
// once coalesced, broadcast via width-32 shuffles. On a segment boundary the
// partial sum is scaled by 1/denom[g] and flushed with 4 atomicAdds per lane
// (~2M atomics total vs 128M naive).
// ---------------------------------------------------------------------------
extern "C" __global__ __launch_bounds__(256) void k_accum(
    const float* __restrict__ H, const int* __restrict__ batch,
    const float* __restrict__ e_arr, const float* __restrict__ denom,
    float* __restrict__ out, int n)
{
    const int NPG = 32; // nodes per 32-lane group
    long long gid  = ((long long)blockIdx.x * 256 + threadIdx.x) >> 5;
    int lane = threadIdx.x & 31;
    long long start = gid * NPG;
    if (start >= n) return;
    int cnt = (int)((n - start < NPG) ? (n - start) : NPG);

    float el = 0.0f;
    int   bl = 0;
    if (lane < cnt) {
        el = e_arr[start + lane];
        bl = batch[start + lane];
    }

    float4 acc = make_float4(0.0f, 0.0f, 0.0f, 0.0f);
    int gprev = __shfl(bl, 0, 32);
    const float* hp = H + (size_t)start * IN_DIM + lane * 4;

    for (int t = 0; t < cnt; ++t) {
        int   g = __shfl(bl, t, 32);
        float e = __shfl(el, t, 32);
        if (g != gprev) {
            float inv = 1.0f / denom[gprev];
            float* o = out + (size_t)gprev * IN_DIM + lane * 4;
            atomicAdd(o + 0, acc.x * inv);
            atomicAdd(o + 1, acc.y * inv);
            atomicAdd(o + 2, acc.z * inv);
            atomicAdd(o + 3, acc.w * inv);
            acc = make_float4(0.0f, 0.0f, 0.0f, 0.0f);
            gprev = g;
        }
        float4 h = *(const float4*)(hp + (size_t)t * IN_DIM);
        acc.x = fmaf(e, h.x, acc.x);
        acc.y = fmaf(e, h.y, acc.y);
        acc.z = fmaf(e, h.z, acc.z);
        acc.w = fmaf(e, h.w, acc.w);
    }
    {
        float inv = 1.0f / denom[gprev];
        float* o = out + (size_t)gprev * IN_DIM + lane * 4;
        atomicAdd(o + 0, acc.x * inv);
        atomicAdd(o + 1, acc.y * inv);
        atomicAdd(o + 2, acc.z * inv);
        atomicAdd(o + 3, acc.w * inv);
    }
}

// ---------------------------------------------------------------------------
// Inputs (setup_inputs order): H [N,128] f32, w1 [64,128] f32, w2 [1,64] f32,
// batch [N] int (sorted), size (scalar, unused host-side: G = out_size/128).
// ws layout: e_arr[N] floats, then denom[G] floats ( (N+G)*4 ~ 4.04 MB ).
// ---------------------------------------------------------------------------
extern "C" void kernel_launch(void* const* d_in, const int* in_sizes, int n_in,
                              void* d_out, int out_size, void* d_ws, size_t ws_size,
                              hipStream_t stream)
{
    const float* H     = (const float*)d_in[0];
    const float* w1    = (const float*)d_in[1];
    const float* w2    = (const float*)d_in[2];
    const int*   batch = (const int*)d_in[3];
    float*       out   = (float*)d_out;

    int n = in_sizes[0] / IN_DIM;   // 1,000,000
    int G = out_size / IN_DIM;      // 10,000

    float* e_arr = (float*)d_ws;
    float* denom = e_arr + n;

    // out and denom must start at 0 (harness poisons with 0xAA).
    hipMemsetAsync(d_out, 0, (size_t)out_size * sizeof(float), stream);
    hipMemsetAsync(denom, 0, (size_t)G * sizeof(float), stream);

    int blocks1 = (n + 255) / 256;
    k_score<<<blocks1, 256, 0, stream>>>(H, w1, w2, batch, e_arr, denom, n);

    long long groups  = ((long long)n + 31) / 32;
    int       blocks2 = (int)((groups + 7) / 8);
    k_accum<<<blocks2, 256, 0, stream>>>(H, batch, e_arr, denom, out, n);
}

// Round 2
// 1279.994 us; speedup vs baseline: 1.1142x; 1.1142x over previous
//
#include <hip/hip_runtime.h>
#include <hip/hip_bf16.h>
#include <math.h>

#define IN_DIM 128
#define HID_DIM 64
#define NPG 64   // nodes per 32-lane group in k_accum

// ---------------------------------------------------------------------------
// fast tanh: tanh(x) = sign(x) * (1 - z) / (1 + z),  z = exp(-2|x|)
// ---------------------------------------------------------------------------
__device__ __forceinline__ float fast_tanh(float x) {
    float ax = fabsf(x);
    float z  = __expf(-2.0f * ax);
    float t  = (1.0f - z) * __builtin_amdgcn_rcpf(1.0f + z);
    return copysignf(t, x);
}

// ---------------------------------------------------------------------------
// K1: per-node score, lane = node. __launch_bounds__(256,4) gives a 128-VGPR
// budget so y[64] stays resident (round-1 compiler fissioned the j-loop at
// VGPR=44, re-reading h 4x -> 820us). w1 read as uniform float4 -> s_load_
// dwordx4 (scalar pipe, free of VALU). |s| <= ||w2||_1 (~6.4) so exp(s) can't
// overflow: segment-max pass skipped (mathematically identical softmax).
// No atomics here anymore: denom is accumulated in K2, applied in K3.
// ---------------------------------------------------------------------------
extern "C" __global__ __launch_bounds__(256, 4) void k_score(
    const float* __restrict__ H, const float* __restrict__ w1,
    const float* __restrict__ w2, float* __restrict__ e_arr, int n)
{
    int i = blockIdx.x * 256 + threadIdx.x;
    if (i >= n) return;

    const float4* h4  = (const float4*)(H + (size_t)i * IN_DIM);
    const float4* w14 = (const float4*)w1;

    float y[HID_DIM];
#pragma unroll
    for (int j = 0; j < HID_DIM; ++j) y[j] = 0.0f;

#pragma unroll 2
    for (int kt = 0; kt < IN_DIM / 4; ++kt) {
        float4 h = h4[kt];
#pragma unroll
        for (int j = 0; j < HID_DIM; ++j) {
            float4 w = w14[j * (IN_DIM / 4) + kt];  // uniform -> s_load_dwordx4
            float a = y[j];
            a = fmaf(w.x, h.x, a);
            a = fmaf(w.y, h.y, a);
            a = fmaf(w.z, h.z, a);
            a = fmaf(w.w, h.w, a);
            y[j] = a;
        }
    }

    float s = 0.0f;
#pragma unroll
    for (int j = 0; j < HID_DIM; ++j)
        s = fmaf(w2[j], fast_tanh(y[j]), s);

    e_arr[i] = __expf(s);
}

// ---------------------------------------------------------------------------
// K2: unnormalized weighted feature sum + denom accumulation, exploiting
// SORTED batch. 32-lane group owns NPG=64 contiguous nodes; lane owns dims
// [4*lane, 4*lane+4) -> each per-node load is a contiguous 512B half-wave
// burst. e/batch preloaded per lane, broadcast via width-32 shuffles. Loads
// batched 8-deep (hbuf) so ~8 are in flight per group (round-1 had 1 ->
// latency-bound 0.85 TB/s). Segment boundary -> flush raw acc + esum
// (~27k flushes total). Normalization deferred to K3.
// ---------------------------------------------------------------------------
extern "C" __global__ __launch_bounds__(256) void k_accum(
    const float* __restrict__ H, const int* __restrict__ batch,
    const float* __restrict__ e_arr, float* __restrict__ out,
    float* __restrict__ denom, int n)
{
    long long grp  = ((long long)blockIdx.x * 256 + threadIdx.x) >> 5;
    int lane = threadIdx.x & 31;
    long long start = grp * NPG;
    if (start >= n) return;
    int cnt = (int)((n - start < NPG) ? (n - start) : NPG);

    float e0 = 0.f, e1 = 0.f;
    int   b0 = 0,   b1 = 0;
    if (lane < cnt)      { e0 = e_arr[start + lane];      b0 = batch[start + lane]; }
    if (32 + lane < cnt) { e1 = e_arr[start + 32 + lane]; b1 = batch[start + 32 + lane]; }

    const float* hp = H + (size_t)start * IN_DIM + lane * 4;
    float4 acc = make_float4(0.f, 0.f, 0.f, 0.f);
    float esum = 0.f;
    int gcur = __shfl(b0, 0, 32);

    auto flush = [&](int g) {
        float* o = out + (size_t)g * IN_DIM + lane * 4;
        atomicAdd(o + 0, acc.x);
        atomicAdd(o + 1, acc.y);
        atomicAdd(o + 2, acc.z);
        atomicAdd(o + 3, acc.w);
        if (lane == 0) atomicAdd(&denom[g], esum);
        acc = make_float4(0.f, 0.f, 0.f, 0.f);
        esum = 0.f;
    };

    auto step = [&](int t, float4 h) {
        int   g = __shfl((t < 32) ? b0 : b1, t & 31, 32);
        float e = __shfl((t < 32) ? e0 : e1, t & 31, 32);
        if (g != gcur) { flush(gcur); gcur = g; }   // group-uniform branch
        acc.x = fmaf(e, h.x, acc.x);
        acc.y = fmaf(e, h.y, acc.y);
        acc.z = fmaf(e, h.z, acc.z);
        acc.w = fmaf(e, h.w, acc.w);
        esum += e;
    };

    if (cnt == NPG) {
#pragma unroll 1
        for (int tb = 0; tb < NPG; tb += 8) {
            float4 hbuf[8];
#pragma unroll
            for (int u = 0; u < 8; ++u)
                hbuf[u] = *(const float4*)(hp + (size_t)(tb + u) * IN_DIM);
#pragma unroll
            for (int u = 0; u < 8; ++u)
                step(tb + u, hbuf[u]);
        }
    } else {
        for (int t = 0; t < cnt; ++t) {
            float4 h = *(const float4*)(hp + (size_t)t * IN_DIM);
            step(t, h);
        }
    }
    flush(gcur);
}

// ---------------------------------------------------------------------------
// K3: out[g][:] *= 1/denom[g]. Empty segments: denom==0 -> write 0 (matches
// reference's isfinite guard: empty segment_sum == 0). 1.28M floats, ~10us.
// ---------------------------------------------------------------------------
extern "C" __global__ __launch_bounds__(256) void k_scale(
    float* __restrict__ out, const float* __restrict__ denom, int G)
{
    int i = blockIdx.x * 256 + threadIdx.x;     // one float4 per thread
    int total4 = G * (IN_DIM / 4);
    if (i >= total4) return;
    int g = i / (IN_DIM / 4);
    float d = denom[g];
    float inv = (d != 0.0f) ? __builtin_amdgcn_rcpf(d) : 0.0f;
    float4* o = (float4*)out + i;
    float4 v = *o;
    v.x *= inv; v.y *= inv; v.z *= inv; v.w *= inv;
    *o = v;
}

// ---------------------------------------------------------------------------
// Inputs: H [N,128] f32, w1 [64,128] f32, w2 [1,64] f32, batch [N] int
// (sorted), size scalar. ws: e_arr[N] + denom[G] floats (~4.04 MB).
// ---------------------------------------------------------------------------
extern "C" void kernel_launch(void* const* d_in, const int* in_sizes, int n_in,
                              void* d_out, int out_size, void* d_ws, size_t ws_size,
                              hipStream_t stream)
{
    const float* H     = (const float*)d_in[0];
    const float* w1    = (const float*)d_in[1];
    const float* w2    = (const float*)d_in[2];
    const int*   batch = (const int*)d_in[3];
    float*       out   = (float*)d_out;

    int n = in_sizes[0] / IN_DIM;   // 1,000,000
    int G = out_size / IN_DIM;      // 10,000

    float* e_arr = (float*)d_ws;
    float* denom = e_arr + n;

    hipMemsetAsync(d_out, 0, (size_t)out_size * sizeof(float), stream);
    hipMemsetAsync(denom, 0, (size_t)G * sizeof(float), stream);

    int blocks1 = (n + 255) / 256;
    k_score<<<blocks1, 256, 0, stream>>>(H, w1, w2, e_arr, n);

    long long groups = ((long long)n + NPG - 1) / NPG;
    long long thr    = groups * 32;
    int blocks2 = (int)((thr + 255) / 256);
    k_accum<<<blocks2, 256, 0, stream>>>(H, batch, e_arr, out, denom, n);

    int total4  = G * (IN_DIM / 4);
    int blocks3 = (total4 + 255) / 256;
    k_scale<<<blocks3, 256, 0, stream>>>(out, denom, G);
}

// Round 3
// 779.610 us; speedup vs baseline: 1.8293x; 1.6418x over previous
//
#include <hip/hip_runtime.h>
#include <hip/hip_bf16.h>
#include <math.h>

#define IN_DIM 128
#define HID_DIM 64

typedef __attribute__((ext_vector_type(8))) short short8;   // 8 bf16 (4 VGPRs)
typedef __attribute__((ext_vector_type(4))) float floatx4;  // MFMA C/D frag

// ---------------------------------------------------------------------------
// fp32 -> bf16 with round-to-nearest-even (3 VALU ops).
// ---------------------------------------------------------------------------
__device__ __forceinline__ short f2bf(float f) {
    unsigned u = __float_as_uint(f);
    u += 0x7FFFu + ((u >> 16) & 1u);
    return (short)(u >> 16);
}

__device__ __forceinline__ short8 pack_bf16(float4 f0, float4 f1) {
    short8 r;
    r[0] = f2bf(f0.x); r[1] = f2bf(f0.y); r[2] = f2bf(f0.z); r[3] = f2bf(f0.w);
    r[4] = f2bf(f1.x); r[5] = f2bf(f1.y); r[6] = f2bf(f1.z); r[7] = f2bf(f1.w);
    return r;
}

// fast tanh: tanh(x) = sign(x)*(1-z)/(1+z), z = exp(-2|x|)
__device__ __forceinline__ float fast_tanh(float x) {
    float ax = fabsf(x);
    float z  = __expf(-2.0f * ax);
    float t  = (1.0f - z) * __builtin_amdgcn_rcpf(1.0f + z);
    return copysignf(t, x);
}

// ---------------------------------------------------------------------------
// K1: scores via bf16 MFMA. Wave owns 64 nodes (4 m-tiles of 16). K=128 in 4
// chunks of 32. Fragment layouts (learn_hip m89/m120 verified):
//   A[m][k]: m = lane&15, k = (lane>>4)*8 + j   (j = vector elem 0..7)
//   B[k][n]: n = lane&15, k = (lane>>4)*8 + j   -> 8 consecutive floats of
//            w1 row n (w1 is [64][128] row-major, B = w1^T)
//   C/D    : col n = lane&15, row m = (lane>>4)*4 + reg
// w1 frags (all 16) converted once -> 64 VGPRs, reused across 4 m-tiles.
// Epilogue: s = sum_n w2[n]*tanh(X[m][n]) via per-lane partials + 16-lane
// butterfly; lane col==0 of each quad stores float4 of exp(s) for 4 nodes.
// |s| <= ||w2||_1 (~6.4) so exp never overflows -> segment-max pass skipped
// (mathematically identical softmax).
// MFMA pins acc/frags in VGPRs -> no j-loop fission (rounds 1-2 pathology).
// ---------------------------------------------------------------------------
extern "C" __global__ __launch_bounds__(256, 3) void k_score(
    const float* __restrict__ H, const float* __restrict__ w1,
    const float* __restrict__ w2, float* __restrict__ e_arr, int n)
{
    const int wave = threadIdx.x >> 6;
    const int lane = threadIdx.x & 63;
    const int col  = lane & 15;
    const int quad = lane >> 4;
    const int base = (blockIdx.x * 4 + wave) * 64;   // first node of this wave

    // ---- B fragments: w1 -> bf16, bf[t][c], t = n-tile, c = k-chunk ----
    short8 bf[4][4];
    {
        const float* wb = w1 + (size_t)col * IN_DIM + quad * 8;
#pragma unroll
        for (int t = 0; t < 4; ++t) {
            const float* wt = wb + t * 16 * IN_DIM;
#pragma unroll
            for (int c = 0; c < 4; ++c) {
                float4 f0 = *(const float4*)(wt + c * 32);
                float4 f1 = *(const float4*)(wt + c * 32 + 4);
                bf[t][c] = pack_bf16(f0, f1);
            }
        }
    }

    floatx4 acc[4][4];   // [m-tile][n-tile]
#pragma unroll
    for (int mt = 0; mt < 4; ++mt)
#pragma unroll
        for (int t = 0; t < 4; ++t)
            acc[mt][t] = (floatx4){0.f, 0.f, 0.f, 0.f};

    // clamped row pointers (tail block: duplicate row n-1, stores guarded)
    const float* hrow[4];
#pragma unroll
    for (int mt = 0; mt < 4; ++mt) {
        int node = base + mt * 16 + col;
        if (node >= n) node = n - 1;
        hrow[mt] = H + (size_t)node * IN_DIM + quad * 8;
    }

#pragma unroll
    for (int c = 0; c < 4; ++c) {
#pragma unroll
        for (int mt = 0; mt < 4; ++mt) {
            float4 f0 = *(const float4*)(hrow[mt] + c * 32);
            float4 f1 = *(const float4*)(hrow[mt] + c * 32 + 4);
            short8 a = pack_bf16(f0, f1);
#pragma unroll
            for (int t = 0; t < 4; ++t)
                acc[mt][t] = __builtin_amdgcn_mfma_f32_16x16x32_bf16(
                    a, bf[t][c], acc[mt][t], 0, 0, 0);
        }
    }

    // ---- epilogue: w2 . tanh(X), 16-lane butterfly, exp, store ----
    float w2v[4];
#pragma unroll
    for (int t = 0; t < 4; ++t) w2v[t] = w2[t * 16 + col];

#pragma unroll
    for (int mt = 0; mt < 4; ++mt) {
        float s[4];
#pragma unroll
        for (int r = 0; r < 4; ++r) {
            float p = 0.f;
#pragma unroll
            for (int t = 0; t < 4; ++t)
                p = fmaf(w2v[t], fast_tanh(acc[mt][t][r]), p);
            p += __shfl_xor(p, 1);
            p += __shfl_xor(p, 2);
            p += __shfl_xor(p, 4);
            p += __shfl_xor(p, 8);
            s[r] = p;
        }
        if (col == 0) {
            int node4 = base + mt * 16 + quad * 4;   // rows quad*4 + 0..3
            if (node4 + 3 < n) {
                float4 ev = make_float4(__expf(s[0]), __expf(s[1]),
                                        __expf(s[2]), __expf(s[3]));
                *(float4*)(e_arr + node4) = ev;
            } else {
#pragma unroll
                for (int r = 0; r < 4; ++r)
                    if (node4 + r < n) e_arr[node4 + r] = __expf(s[r]);
            }
        }
    }
}

// ---------------------------------------------------------------------------
// K2: one 32-lane group per segment (batch sorted). Binary-search [lo,hi),
// then a branch-free stream: lane owns dims [4*lane,4*lane+4) (512B/node,
// perfectly coalesced), e via same-address broadcast load. 8-deep prefetch
// keeps ~8 float4 loads in flight per group. Exclusive segment ownership ->
// ZERO atomics; out[g] = acc/sum(e) written directly (empty segment -> 0,
// matching the reference's isfinite guard).
// ---------------------------------------------------------------------------
extern "C" __global__ __launch_bounds__(256) void k_accum(
    const float* __restrict__ H, const int* __restrict__ batch,
    const float* __restrict__ e_arr, float* __restrict__ out, int n, int G)
{
    int g    = (int)((blockIdx.x * 256 + threadIdx.x) >> 5);
    int lane = threadIdx.x & 31;
    if (g >= G) return;

    // lower_bound(batch, g) and lower_bound(batch, g+1); batch is L2-hot.
    int lo = 0, hi = n;
    while (lo < hi) { int mid = (lo + hi) >> 1; if (batch[mid] < g) lo = mid + 1; else hi = mid; }
    int lo2 = lo, hi2 = n;
    while (lo2 < hi2) { int mid = (lo2 + hi2) >> 1; if (batch[mid] < g + 1) lo2 = mid + 1; else hi2 = mid; }
    int cnt = lo2 - lo;

    const float* hp = H + (size_t)lo * IN_DIM + lane * 4;
    const float* ep = e_arr + lo;

    float4 acc = make_float4(0.f, 0.f, 0.f, 0.f);
    float esum = 0.f;

    int t = 0;
    for (; t + 8 <= cnt; t += 8) {
        float4 hb[8];
        float  eb[8];
#pragma unroll
        for (int u = 0; u < 8; ++u) {
            hb[u] = *(const float4*)(hp + (size_t)(t + u) * IN_DIM);
            eb[u] = ep[t + u];
        }
#pragma unroll
        for (int u = 0; u < 8; ++u) {
            acc.x = fmaf(eb[u], hb[u].x, acc.x);
            acc.y = fmaf(eb[u], hb[u].y, acc.y);
            acc.z = fmaf(eb[u], hb[u].z, acc.z);
            acc.w = fmaf(eb[u], hb[u].w, acc.w);
            esum += eb[u];
        }
    }
    for (; t < cnt; ++t) {
        float4 h = *(const float4*)(hp + (size_t)t * IN_DIM);
        float  e = ep[t];
        acc.x = fmaf(e, h.x, acc.x);
        acc.y = fmaf(e, h.y, acc.y);
        acc.z = fmaf(e, h.z, acc.z);
        acc.w = fmaf(e, h.w, acc.w);
        esum += e;
    }

    float inv = (esum != 0.f) ? 1.0f / esum : 0.f;
    float4 o = make_float4(acc.x * inv, acc.y * inv, acc.z * inv, acc.w * inv);
    *(float4*)(out + (size_t)g * IN_DIM + lane * 4) = o;
}

// ---------------------------------------------------------------------------
// Inputs: H [N,128] f32, w1 [64,128] f32, w2 [1,64] f32, batch [N] int32
// (sorted), size scalar. ws: e_arr[N] floats. No memsets needed: e_arr and
// out are fully written every call.
// ---------------------------------------------------------------------------
extern "C" void kernel_launch(void* const* d_in, const int* in_sizes, int n_in,
                              void* d_out, int out_size, void* d_ws, size_t ws_size,
                              hipStream_t stream)
{
    const float* H     = (const float*)d_in[0];
    const float* w1    = (const float*)d_in[1];
    const float* w2    = (const float*)d_in[2];
    const int*   batch = (const int*)d_in[3];
    float*       out   = (float*)d_out;

    int n = in_sizes[0] / IN_DIM;   // 1,000,000
    int G = out_size / IN_DIM;      // 10,000

    float* e_arr = (float*)d_ws;

    int blocks1 = (n + 255) / 256;  // 256 nodes per block (4 waves x 64)
    k_score<<<blocks1, 256, 0, stream>>>(H, w1, w2, e_arr, n);

    int blocks2 = (G * 32 + 255) / 256;
    k_accum<<<blocks2, 256, 0, stream>>>(H, batch, e_arr, out, n, G);
}